// Round 1
// 1380.954 us; speedup vs baseline: 2.1323x; 2.1323x over previous
//
#include <hip/hip_runtime.h>
#include <hip/hip_bf16.h>

// Elman RNN: B=128, T=256, I=512, H=1024
//   Phase 1: xp[b,h] per t  (big MFMA GEMM, bf16)
//   Phase 2: ONE persistent kernel for all 256 steps, restructured:
//     - 8 INDEPENDENT batch-group chains (16 rows each), own counter each
//       -> barrier fan-in 8 (was 256), no cross-group coupling.
//     - W_hh resident in VGPRs (32 b-frags = 128 VGPR/lane, loaded once):
//       each wave owns 16 cols x full K=1024 -> no k-half reduce barriers.
//     - h staged per block into XOR-swizzled LDS via agent-scope 8B atomic
//       loads (MALL-coherent); ds_read_b128 a-frags ~conflict-free.
//     - states stores issued AFTER the arrive so HBM latency overlaps spin.
// Precision: bf16 inputs, fp32 MFMA accumulate, fp32 tanh, fp32 output.

#define B_SZ 128
#define T_SZ 256
#define I_SZ 512
#define H_SZ 1024

#define GROUPS 8                      // independent batch groups of 16 rows
#define BLK_PG 8                      // blocks per group (128 cols each)
#define GRID_P (GROUPS * BLK_PG)      // 64 persistent blocks
#define THR_P  512                    // 8 waves: 16 cols x K=1024 each

typedef __bf16 bf16x8 __attribute__((ext_vector_type(8)));
typedef __bf16 bf16x4 __attribute__((ext_vector_type(4)));
typedef float f32x4 __attribute__((ext_vector_type(4)));
typedef unsigned long long u64;

__device__ __forceinline__ float fast_tanh(float x) {
    // exact at +-inf saturation, ~1e-6 abs err; bf16 noise dominates anyway
    return 1.0f - 2.0f / (__expf(2.0f * x) + 1.0f);
}

// ---------------- fp32 -> bf16 convert (vectorized x4) ----------------
__global__ void cvt_kernel(const float* __restrict__ src, __bf16* __restrict__ dst, int n4) {
    int i = blockIdx.x * blockDim.x + threadIdx.x;
    if (i < n4) {
        float4 v = reinterpret_cast<const float4*>(src)[i];
        bf16x4 o;
        o[0] = (__bf16)v.x; o[1] = (__bf16)v.y; o[2] = (__bf16)v.z; o[3] = (__bf16)v.w;
        reinterpret_cast<bf16x4*>(dst)[i] = o;
    }
}

// ---------------- input projection -> xp stored [T,B,H] ----------------
__global__ __launch_bounds__(256) void proj_kernel(const __bf16* __restrict__ x,
                                                   const __bf16* __restrict__ wih,
                                                   const float* __restrict__ bih,
                                                   __bf16* __restrict__ xp) {
    const int m0   = blockIdx.x * 16;      // bt row tile
    const int n0   = blockIdx.y * 64;
    const int lane = threadIdx.x & 63;
    const int wave = threadIdx.x >> 6;
    const int lm   = lane & 15;
    const int quad = lane >> 4;
    const int nw   = n0 + wave * 16;

    f32x4 acc = {0.f, 0.f, 0.f, 0.f};
    const __bf16* arow = x   + (size_t)(m0 + lm) * I_SZ + quad * 8;
    const __bf16* brow = wih + (size_t)(nw + lm) * I_SZ + quad * 8;
#pragma unroll 4
    for (int k = 0; k < I_SZ; k += 32) {
        bf16x8 a = *reinterpret_cast<const bf16x8*>(arow + k);
        bf16x8 b = *reinterpret_cast<const bf16x8*>(brow + k);
        acc = __builtin_amdgcn_mfma_f32_16x16x32_bf16(a, b, acc, 0, 0, 0);
    }
    const int col  = nw + lm;
    const float bias = bih[col];
#pragma unroll
    for (int r = 0; r < 4; ++r) {
        int row = m0 + quad * 4 + r;       // bt index: b = row>>8, t = row&255
        int b   = row >> 8;
        int t   = row & (T_SZ - 1);
        xp[((size_t)t * B_SZ + b) * H_SZ + col] = (__bf16)(acc[r] + bias);
    }
}

// ---------------- persistent recurrence ----------------
// 64 blocks x 512 threads. block = 16 batch rows x 128 cols, wave = 16 cols.
// group g = bid>>3 (8 groups of 16 batch rows), col block cb = bid&7.
__global__ __launch_bounds__(THR_P, 2) void rnn_persist(const __bf16* __restrict__ whh,
                                                        const __bf16* __restrict__ xp,
                                                        const float* __restrict__ bhh,
                                                        __bf16* __restrict__ hA,
                                                        __bf16* __restrict__ hB,
                                                        float* __restrict__ states,
                                                        float* __restrict__ hlast,
                                                        unsigned* __restrict__ cnt) {
    __shared__ __align__(16) __bf16 hlds[16 * H_SZ];   // 32 KB, XOR-swizzled h tile
    __shared__ __align__(16) __bf16 htile[16 * 128];   // 4 KB packed next-h

    const int tid  = threadIdx.x;
    const int lane = tid & 63;
    const int wave = tid >> 6;             // 0..7
    const int lm   = lane & 15;
    const int quad = lane >> 4;
    const int bid  = blockIdx.x;
    const int g    = bid >> 3;             // batch group
    const int cb   = bid & 7;              // col block within group
    const int r0   = g * 16;               // first batch row of group
    const int n0   = cb * 128;             // first col of block
    const int col  = n0 + wave * 16 + lm;  // this lane's output col

    // ---- W_hh fragments resident in VGPRs: 16 cols x K=1024 per wave ----
    bf16x8 wfrag[32];
    {
        const __bf16* wp = whh + (size_t)col * H_SZ + quad * 8;
#pragma unroll
        for (int i = 0; i < 32; ++i)
            wfrag[i] = *reinterpret_cast<const bf16x8*>(wp + i * 32);
    }
    const float bias = bhh[col];
    unsigned* my_cnt = cnt + g * 32;       // per-group counter, 128B apart

    size_t st_base[4];
#pragma unroll
    for (int r = 0; r < 4; ++r)
        st_base[r] = (size_t)(r0 + quad * 4 + r) * T_SZ * H_SZ + col;

    const int srow = (lm & 7) << 4;        // read-side XOR swizzle

    for (int t = 0; t < T_SZ; ++t) {
        const __bf16* cur = (t & 1) ? hB : hA;
        __bf16*       nxt = (t & 1) ? hA : hB;

        // ---- xp prefetch (normal loads; latency hidden under h load) ----
        float xv[4];
#pragma unroll
        for (int r = 0; r < 4; ++r)
            xv[r] = (float)xp[(size_t)t * B_SZ * H_SZ
                              + (size_t)(r0 + quad * 4 + r) * H_SZ + col];

        // ---- cooperative h load: 16 rows x 1024 cols (32 KB) -> swizzled LDS ----
        {
            const u64* src = (const u64*)(cur + (size_t)r0 * H_SZ);
            u64 v[8];
#pragma unroll
            for (int i = 0; i < 8; ++i)
                v[i] = __hip_atomic_load(src + tid + i * THR_P,
                                         __ATOMIC_RELAXED, __HIP_MEMORY_SCOPE_AGENT);
#pragma unroll
            for (int i = 0; i < 8; ++i) {
                int u   = tid + i * THR_P;     // 0..4095
                int row = u >> 8;              // 256 u64 per 2048B row
                int kb  = (u & 255) * 8;       // byte offset in row
                *(u64*)((char*)hlds + row * 2048 + (kb ^ ((row & 7) << 4))) = v[i];
            }
        }
        __syncthreads();

        // ---- MFMA: 16 rows x 16 cols, full K=1024, W from VGPRs ----
        f32x4 acc = {0.f, 0.f, 0.f, 0.f};
#pragma unroll
        for (int i = 0; i < 32; ++i) {
            bf16x8 a = *reinterpret_cast<const bf16x8*>(
                (const char*)hlds + lm * 2048 + ((i * 64 + quad * 16) ^ srow));
            acc = __builtin_amdgcn_mfma_f32_16x16x32_bf16(a, wfrag[i], acc, 0, 0, 0);
        }

        // ---- tanh + pack next-h tile into LDS ----
        float hv[4];
#pragma unroll
        for (int r = 0; r < 4; ++r) {
            float u = acc[r] + xv[r] + bias;
            hv[r] = fast_tanh(u);
            htile[(quad * 4 + r) * 128 + (wave * 16 + lm)] = (__bf16)hv[r];
        }

        if (t < T_SZ - 1) {
            __syncthreads();
            // packed h store: one u64 per thread (16x128 bf16 = 4 KB)
            {
                int row = tid >> 5;            // 32 u64 per 256B row
                int kb  = (tid & 31) * 8;
                __hip_atomic_store((u64*)((char*)nxt + (size_t)(r0 + row) * 2048
                                          + n0 * 2 + kb),
                                   ((const u64*)htile)[tid],
                                   __ATOMIC_RELAXED, __HIP_MEMORY_SCOPE_AGENT);
            }
            __syncthreads();                   // vmcnt(0) drain before arrive
            if (tid == 0)
                __hip_atomic_fetch_add(my_cnt, 1u,
                                       __ATOMIC_RELAXED, __HIP_MEMORY_SCOPE_AGENT);
        }

        // ---- states stores AFTER arrive: HBM latency overlaps the spin ----
#pragma unroll
        for (int r = 0; r < 4; ++r)
            states[st_base[r] + (size_t)t * H_SZ] = hv[r];
        if (t == T_SZ - 1) {
#pragma unroll
            for (int r = 0; r < 4; ++r)
                hlast[(size_t)(r0 + quad * 4 + r) * H_SZ + col] = hv[r];
        }

        if (t < T_SZ - 1) {
            if (tid == 0) {
                const unsigned target = (unsigned)BLK_PG * (unsigned)(t + 1);
                while (__hip_atomic_load(my_cnt, __ATOMIC_RELAXED,
                                         __HIP_MEMORY_SCOPE_AGENT) < target)
                    __builtin_amdgcn_s_sleep(2);
            }
            __syncthreads();
        }
    }
}

extern "C" void kernel_launch(void* const* d_in, const int* in_sizes, int n_in,
                              void* d_out, int out_size, void* d_ws, size_t ws_size,
                              hipStream_t stream) {
    const float* x    = (const float*)d_in[0];   // [B,T,I]
    const float* Wih  = (const float*)d_in[1];   // [H,I]
    const float* Whh  = (const float*)d_in[2];   // [H,H]
    const float* bih  = (const float*)d_in[3];   // [H]
    const float* bhh  = (const float*)d_in[4];   // [H]

    float* states = (float*)d_out;                               // [B,T,H]
    float* hlast  = (float*)d_out + (size_t)B_SZ * T_SZ * H_SZ;  // [B,H]

    // workspace carve (bytes), all 16B aligned
    char* w = (char*)d_ws;
    __bf16* x_bf   = (__bf16*)w;  w += (size_t)B_SZ * T_SZ * I_SZ * 2;  // 33.5 MB
    __bf16* wih_bf = (__bf16*)w;  w += (size_t)H_SZ * I_SZ * 2;         // 1 MB
    __bf16* whh_bf = (__bf16*)w;  w += (size_t)H_SZ * H_SZ * 2;         // 2 MB
    __bf16* xp_bf  = (__bf16*)w;  w += (size_t)B_SZ * T_SZ * H_SZ * 2;  // 67 MB, [T,B,H]
    __bf16* hA     = (__bf16*)w;  w += (size_t)B_SZ * H_SZ * 2;         // 256 KB
    __bf16* hB     = (__bf16*)w;  w += (size_t)B_SZ * H_SZ * 2;         // 256 KB
    unsigned* cnt  = (unsigned*)w; w += 1024;                           // 8 group counters, 128B apart
    (void)ws_size;

    // converts
    {
        int n4 = B_SZ * T_SZ * I_SZ / 4;
        cvt_kernel<<<(n4 + 255) / 256, 256, 0, stream>>>(x, x_bf, n4);
    }
    {
        int n4 = H_SZ * I_SZ / 4;
        cvt_kernel<<<(n4 + 255) / 256, 256, 0, stream>>>(Wih, wih_bf, n4);
    }
    {
        int n4 = H_SZ * H_SZ / 4;
        cvt_kernel<<<(n4 + 255) / 256, 256, 0, stream>>>(Whh, whh_bf, n4);
    }

    // h0 = 0, group counters = 0 (ws is re-poisoned 0xAA before every launch)
    hipMemsetAsync(hA, 0, (size_t)B_SZ * H_SZ * 2, stream);
    hipMemsetAsync(cnt, 0, 1024, stream);

    // input projection
    {
        dim3 grid(B_SZ * T_SZ / 16, H_SZ / 64);  // (2048, 16)
        proj_kernel<<<grid, 256, 0, stream>>>(x_bf, wih_bf, bih, xp_bf);
    }

    // persistent recurrence: 8 independent group chains, fan-in 8 barriers
    rnn_persist<<<GRID_P, THR_P, 0, stream>>>(whh_bf, xp_bf, bhh, hA, hB,
                                              states, hlast, cnt);
}